// Round 3
// baseline (736.679 us; speedup 1.0000x reference)
//
#include <hip/hip_runtime.h>
#include <math.h>

// J=25, F=38400, C=128, B=128. x (J,F,C) fp32, idx sorted, out (J,B,C) fp32.
// Two structural HBM passes over x (491 MB > 256 MB L3): floor ~156 us.
// R3: contiguous-chunk-per-group layout, 8-deep load bursts off one base
// register (imm offsets 0..3584B) -> 8 KB/wave in flight, minimal addr VALU.

__global__ void seg_bounds_kernel(const int* __restrict__ idx, int F, int B,
                                  int* __restrict__ seg) {
    int b = blockIdx.x * blockDim.x + threadIdx.x;
    if (b > B) return;
    int lo = 0, hi = F;
    while (lo < hi) {
        int mid = (lo + hi) >> 1;
        if (idx[mid] < b) lo = mid + 1; else hi = mid;
    }
    seg[b] = lo;
}

__device__ __forceinline__ void f4add(float4& a, const float4& v) {
    a.x += v.x; a.y += v.y; a.z += v.z; a.w += v.w;
}
__device__ __forceinline__ float dot4(const float4& a, const float4& b) {
    return a.x * b.x + a.y * b.y + a.z * b.z + a.w * b.w;
}

// One block per (j,b). 8 groups of 32 lanes; group g owns a contiguous chunk
// of ceil(n/8) frames. Burst of 8 frame-loads per iteration, single base reg.
__global__ void __launch_bounds__(256) seg_mean_kernel(
    const float* __restrict__ x, const int* __restrict__ seg,
    int F, int B, float* __restrict__ mean) {
    const int bid = blockIdx.x;
    const int j = bid / B, b = bid - j * B;
    const int f0 = seg[b], f1 = seg[b + 1];
    const int n = f1 - f0;
    const int tid = threadIdx.x;
    const int lane32 = tid & 31;
    const int g = tid >> 5;

    const int q = (n + 7) >> 3;                 // frames per group chunk
    const int fs = f0 + g * q;
    const int fe = min(fs + q, f1);
    int m = fe - fs;                            // may be <=0 for tail groups

    const float4* p = (const float4*)(x + (size_t)j * F * 128)
                      + (size_t)fs * 32 + lane32;
    float4 a0 = make_float4(0.f, 0.f, 0.f, 0.f);
    float4 a1 = make_float4(0.f, 0.f, 0.f, 0.f);

    while (m >= 8) {
        float4 v0 = p[0],   v1 = p[32],  v2 = p[64],  v3 = p[96];
        float4 v4 = p[128], v5 = p[160], v6 = p[192], v7 = p[224];
        f4add(a0, v0); f4add(a1, v1); f4add(a0, v2); f4add(a1, v3);
        f4add(a0, v4); f4add(a1, v5); f4add(a0, v6); f4add(a1, v7);
        p += 256; m -= 8;
    }
    while (m > 0) { f4add(a0, p[0]); p += 32; --m; }
    f4add(a0, a1);

    __shared__ float4 s[256];
    s[tid] = a0;
    __syncthreads();
#pragma unroll
    for (int stride = 128; stride >= 32; stride >>= 1) {
        if (tid < stride) {
            float4 o = s[tid + stride], mm = s[tid];
            mm.x += o.x; mm.y += o.y; mm.z += o.z; mm.w += o.w;
            s[tid] = mm;
        }
        __syncthreads();
    }
    if (tid < 32) {
        float inv = 1.0f / fmaxf((float)n, 1.0f);
        float4 mm = s[tid];
        ((float4*)(mean + ((size_t)j * B + b) * 128))[tid] =
            make_float4(mm.x * inv, mm.y * inv, mm.z * inv, mm.w * inv);
    }
}

// gc[r,t] = tanh(sum_k mean[r,k] * W[k,t]); W (64 KB) stays L2-resident.
__global__ void gc_kernel(const float* __restrict__ mean,
                          const float* __restrict__ W,
                          float* __restrict__ gc) {
    const int r = blockIdx.x;
    const int t = threadIdx.x;
    __shared__ float srow[128];
    srow[t] = mean[(size_t)r * 128 + t];
    __syncthreads();
    float acc = 0.f;
#pragma unroll 8
    for (int k = 0; k < 128; ++k) acc = fmaf(srow[k], W[k * 128 + t], acc);
    gc[(size_t)r * 128 + t] = tanhf(acc);
}

// One block per (j,b), same chunk layout. 8 independent dot/shuffle/sigmoid
// chains per burst. xor masks <=16 stay inside each 32-lane group; the two
// groups of a wave may diverge in trip count, which is safe (sources of each
// lane's shuffle are within its own active group).
__global__ void __launch_bounds__(256) gate_scatter_kernel(
    const float* __restrict__ x, const float* __restrict__ gc,
    const int* __restrict__ seg, int F, int B,
    float* __restrict__ out) {
    const int bid = blockIdx.x;
    const int j = bid / B, b = bid - j * B;
    const int f0 = seg[b], f1 = seg[b + 1];
    const int n = f1 - f0;
    const int tid = threadIdx.x;
    const int lane32 = tid & 31;
    const int g = tid >> 5;

    const int q = (n + 7) >> 3;
    const int fs = f0 + g * q;
    const int fe = min(fs + q, f1);
    int m = fe - fs;

    const float4* p = (const float4*)(x + (size_t)j * F * 128)
                      + (size_t)fs * 32 + lane32;
    const float4 gv = ((const float4*)(gc + ((size_t)j * B + b) * 128))[lane32];

    float4 a0 = make_float4(0.f, 0.f, 0.f, 0.f);
    float4 a1 = make_float4(0.f, 0.f, 0.f, 0.f);

    while (m >= 8) {
        float4 v0 = p[0],   v1 = p[32],  v2 = p[64],  v3 = p[96];
        float4 v4 = p[128], v5 = p[160], v6 = p[192], v7 = p[224];
        float d0 = dot4(v0, gv), d1 = dot4(v1, gv), d2 = dot4(v2, gv),
              d3 = dot4(v3, gv), d4 = dot4(v4, gv), d5 = dot4(v5, gv),
              d6 = dot4(v6, gv), d7 = dot4(v7, gv);
#pragma unroll
        for (int mk = 16; mk >= 1; mk >>= 1) {
            d0 += __shfl_xor(d0, mk, 64); d1 += __shfl_xor(d1, mk, 64);
            d2 += __shfl_xor(d2, mk, 64); d3 += __shfl_xor(d3, mk, 64);
            d4 += __shfl_xor(d4, mk, 64); d5 += __shfl_xor(d5, mk, 64);
            d6 += __shfl_xor(d6, mk, 64); d7 += __shfl_xor(d7, mk, 64);
        }
        float g0 = 1.0f / (1.0f + __expf(-d0));
        float g1 = 1.0f / (1.0f + __expf(-d1));
        float g2 = 1.0f / (1.0f + __expf(-d2));
        float g3 = 1.0f / (1.0f + __expf(-d3));
        float g4 = 1.0f / (1.0f + __expf(-d4));
        float g5 = 1.0f / (1.0f + __expf(-d5));
        float g6 = 1.0f / (1.0f + __expf(-d6));
        float g7 = 1.0f / (1.0f + __expf(-d7));
        a0.x += g0 * v0.x + g2 * v2.x + g4 * v4.x + g6 * v6.x;
        a0.y += g0 * v0.y + g2 * v2.y + g4 * v4.y + g6 * v6.y;
        a0.z += g0 * v0.z + g2 * v2.z + g4 * v4.z + g6 * v6.z;
        a0.w += g0 * v0.w + g2 * v2.w + g4 * v4.w + g6 * v6.w;
        a1.x += g1 * v1.x + g3 * v3.x + g5 * v5.x + g7 * v7.x;
        a1.y += g1 * v1.y + g3 * v3.y + g5 * v5.y + g7 * v7.y;
        a1.z += g1 * v1.z + g3 * v3.z + g5 * v5.z + g7 * v7.z;
        a1.w += g1 * v1.w + g3 * v3.w + g5 * v5.w + g7 * v7.w;
        p += 256; m -= 8;
    }
    while (m > 0) {
        float4 v = p[0];
        float d = dot4(v, gv);
#pragma unroll
        for (int mk = 16; mk >= 1; mk >>= 1) d += __shfl_xor(d, mk, 64);
        float gg = 1.0f / (1.0f + __expf(-d));
        a0.x += gg * v.x; a0.y += gg * v.y; a0.z += gg * v.z; a0.w += gg * v.w;
        p += 32; --m;
    }
    f4add(a0, a1);

    __shared__ float4 s[256];
    s[tid] = a0;
    __syncthreads();
#pragma unroll
    for (int stride = 128; stride >= 32; stride >>= 1) {
        if (tid < stride) {
            float4 o = s[tid + stride], mm = s[tid];
            mm.x += o.x; mm.y += o.y; mm.z += o.z; mm.w += o.w;
            s[tid] = mm;
        }
        __syncthreads();
    }
    if (tid < 32) {
        float inv = 1.0f / fmaxf((float)n, 1.0f);
        float4 mm = s[tid];
        ((float4*)(out + ((size_t)j * B + b) * 128))[tid] =
            make_float4(mm.x * inv, mm.y * inv, mm.z * inv, mm.w * inv);
    }
}

extern "C" void kernel_launch(void* const* d_in, const int* in_sizes, int n_in,
                              void* d_out, int out_size, void* d_ws, size_t ws_size,
                              hipStream_t stream) {
    const float* x  = (const float*)d_in[0];
    const int* idx  = (const int*)d_in[1];
    const float* W  = (const float*)d_in[3];
    float* out      = (float*)d_out;

    const int F = in_sizes[1];
    int C = 1;
    while ((long long)C * C < (long long)in_sizes[3]) ++C;   // 128
    const int J = in_sizes[0] / (F * C);                     // 25
    const int B = out_size / (J * C);                        // 128

    char* ws = (char*)d_ws;
    int* seg = (int*)ws;
    size_t off = (((size_t)(B + 1) * sizeof(int)) + 255) & ~(size_t)255;
    float* mean = (float*)(ws + off);
    off += (((size_t)J * B * C * sizeof(float)) + 255) & ~(size_t)255;
    float* gcb = (float*)(ws + off);

    seg_bounds_kernel<<<(B + 1 + 255) / 256, 256, 0, stream>>>(idx, F, B, seg);
    seg_mean_kernel<<<J * B, 256, 0, stream>>>(x, seg, F, B, mean);
    gc_kernel<<<J * B, C, 0, stream>>>(mean, W, gcb);
    gate_scatter_kernel<<<J * B, 256, 0, stream>>>(x, gcb, seg, F, B, out);
}